// Round 3
// baseline (1400.108 us; speedup 1.0000x reference)
//
#include <hip/hip_runtime.h>
#include <hip/hip_bf16.h>
#include <stdint.h>

// fp32 I/O. x[8,4096,1024]; Wq/Wk/Wv[1024,1024] (row = out feature); b*[1024].
// Channel-attention collapse:
//   G_b = X_b^T X_b (fp32, stored in d_out scratch), c = X^T 1, diag = sum x^2
//   Z = Wq_h G  (bf16 MFMA, diag handled in fp32)
//   L = 0.125(Z Wk_h^T + bq uk^T + uq bk^T + 4096 bq bk^T); P = softmax_e
//   Wo[hd,:] = sum_e P[d,e] Wv[he,:]  (bf16, ws); bo = P bv
//   Out_b = X_b Wo_b^T + bo  (fp32 out, overwrites G region last)

#define B_   8
#define S_   4096
#define E_   1024
#define H_   16

typedef float floatx4 __attribute__((ext_vector_type(4)));
typedef short short8  __attribute__((ext_vector_type(8)));

#define MFMA(a,b,c) __builtin_amdgcn_mfma_f32_16x16x32_bf16((a),(b),(c),0,0,0)

static __device__ __forceinline__ unsigned short f2bf(float x){
    __hip_bfloat16 h = __float2bfloat16(x);
    return __builtin_bit_cast(unsigned short, h);
}
static __device__ __forceinline__ float bf2f(unsigned short u){
    unsigned int w = ((unsigned int)u) << 16;
    return __builtin_bit_cast(float, w);
}
static __device__ __forceinline__ short8 lds_load8(const unsigned short* p) {
    union { ushort4 u4[2]; short8 s8; } f;
    f.u4[0] = *(const ushort4*)(p);
    f.u4[1] = *(const ushort4*)(p + 4);
    return f.s8;
}
// Transposed buffers (stride 64 shorts, 8 chunks of 8): phys = chunk ^ f(row)
static __device__ __forceinline__ int swz(int chunk, int row){
    return chunk ^ ((row >> 3) & 7) ^ (row & 7);
}
// Row-major k-contiguous buffer, stride 128 shorts, 16 chunks XOR row&15.
static __device__ __forceinline__ int rk_idx(int row, int col){
    return row * 128 + (((col >> 3) ^ (row & 15)) << 3) + (col & 7);
}

// ---------------------------------------------------------------------------
// Partial sums: cpart[chunk][b][e] = sum_{s in chunk} x ; d2part = sum x^2
// ---------------------------------------------------------------------------
__global__ __launch_bounds__(256) void sums_kernel(
    const float* __restrict__ X, float* __restrict__ cpart, float* __restrict__ d2part)
{
    const int b = blockIdx.y, chunk = blockIdx.z;
    const int e = blockIdx.x * 256 + threadIdx.x;
    const float* p = X + ((size_t)b * S_ + chunk * 256) * E_ + e;
    float s1 = 0.f, s2 = 0.f;
#pragma unroll 8
    for (int i = 0; i < 256; ++i) {
        float v = p[(size_t)i * E_];
        s1 += v; s2 += v * v;
    }
    cpart [(chunk * B_ + b) * E_ + e] = s1;
    d2part[(chunk * B_ + b) * E_ + e] = s2;
}

__global__ __launch_bounds__(256) void reduce_kernel(
    const float* __restrict__ cpart, const float* __restrict__ d2part,
    float* __restrict__ c, float* __restrict__ gdiag)
{
    const int idx = blockIdx.x * 256 + threadIdx.x;   // b*1024+e, 8192 total
    const int b = idx >> 10, e = idx & 1023;
    float s1 = 0.f, s2 = 0.f;
#pragma unroll
    for (int p = 0; p < 16; ++p) {
        s1 += cpart [(p * B_ + b) * E_ + e];
        s2 += d2part[(p * B_ + b) * E_ + e];
    }
    c[idx] = s1; gdiag[idx] = s2;
}

// ---------------------------------------------------------------------------
// uq[b][j] = Wq[j,:]·c_b ; uk[b][j] = Wk[j,:]·c_b   (all fp32)
// ---------------------------------------------------------------------------
__global__ __launch_bounds__(256) void uqk_kernel(
    const float* __restrict__ Wq, const float* __restrict__ Wk,
    const float* __restrict__ c, float* __restrict__ uq, float* __restrict__ uk)
{
    const int b = blockIdx.y;
    const int j = blockIdx.x * 256 + threadIdx.x;
    const float* cb = c + b * E_;
    const float* q = Wq + (size_t)j * E_;
    const float* k = Wk + (size_t)j * E_;
    float sq = 0.f, sk = 0.f;
    for (int i = 0; i < E_; i += 4) {
        float4 vq = *(const float4*)(q + i);
        float4 vk = *(const float4*)(k + i);
        float4 cv = *(const float4*)(cb + i);
        sq += vq.x*cv.x + vq.y*cv.y + vq.z*cv.z + vq.w*cv.w;
        sk += vk.x*cv.x + vk.y*cv.y + vk.z*cv.z + vk.w*cv.w;
    }
    uq[b * E_ + j] = sq;
    uk[b * E_ + j] = sk;
}

// ---------------------------------------------------------------------------
// Gram: G_b = X_b^T X_b, fp32 out. 36 upper-tri 128x128 tile pairs x 8 batches.
// fp32 X -> bf16 transposed LDS staging ([e][s], swz); 16x16x32 MFMA.
// Straight write + scattered mirror write for off-diag tiles.
// ---------------------------------------------------------------------------
__global__ __launch_bounds__(256) void gram_kernel(
    const float* __restrict__ X, float* __restrict__ G)
{
    const int b = blockIdx.y;
    int u = blockIdx.x, mb = 0;
    while (u >= 8 - mb) { u -= 8 - mb; ++mb; }
    const int nb = mb + u;
    const int m0 = mb * 128, n0 = nb * 128;
    const bool diag = (mb == nb);
    const int t = threadIdx.x, lane = t & 63, w = t >> 6;
    const int l15 = lane & 15, quad = lane >> 4;
    const int mw = 64 * (w >> 1), nw = 64 * (w & 1);

    __shared__ __align__(16) unsigned short At[128 * 64];
    __shared__ __align__(16) unsigned short Bt[128 * 64];

    const floatx4 fz = {0.f, 0.f, 0.f, 0.f};
    floatx4 acc[4][4];
#pragma unroll
    for (int i = 0; i < 4; ++i)
#pragma unroll
        for (int j = 0; j < 4; ++j) acc[i][j] = fz;

    const float* Xb = X + (size_t)b * S_ * E_;

    for (int s0 = 0; s0 < S_; s0 += 64) {
        __syncthreads();
#pragma unroll
        for (int it = 0; it < 8; ++it) {
            const int l = t + 256 * it;        // 0..2047
            const int e4 = l & 31, sl = l >> 5; // e4: float4 col, sl: 0..63
            float4 va = *(const float4*)(Xb + (size_t)(s0 + sl) * E_ + m0 + e4 * 4);
            const float av[4] = {va.x, va.y, va.z, va.w};
#pragma unroll
            for (int j = 0; j < 4; ++j) {
                const int e = e4 * 4 + j;
                At[e * 64 + swz(sl >> 3, e) * 8 + (sl & 7)] = f2bf(av[j]);
            }
            if (!diag) {
                float4 vb = *(const float4*)(Xb + (size_t)(s0 + sl) * E_ + n0 + e4 * 4);
                const float bvv[4] = {vb.x, vb.y, vb.z, vb.w};
#pragma unroll
                for (int j = 0; j < 4; ++j) {
                    const int e = e4 * 4 + j;
                    Bt[e * 64 + swz(sl >> 3, e) * 8 + (sl & 7)] = f2bf(bvv[j]);
                }
            }
        }
        __syncthreads();
        const unsigned short* Bp = diag ? At : Bt;
#pragma unroll
        for (int ks = 0; ks < 2; ++ks) {
            const int q = ks * 4 + quad;
            short8 af[4], bfr[4];
#pragma unroll
            for (int i = 0; i < 4; ++i) {
                const int row = mw + 16 * i + l15;
                af[i] = lds_load8(&At[row * 64 + swz(q, row) * 8]);
            }
#pragma unroll
            for (int j = 0; j < 4; ++j) {
                const int row = nw + 16 * j + l15;
                bfr[j] = lds_load8(&Bp[row * 64 + swz(q, row) * 8]);
            }
#pragma unroll
            for (int i = 0; i < 4; ++i)
#pragma unroll
                for (int j = 0; j < 4; ++j)
                    acc[i][j] = MFMA(af[i], bfr[j], acc[i][j]);
        }
    }

    float* Gb = G + (size_t)b * E_ * E_;
#pragma unroll
    for (int jt = 0; jt < 4; ++jt)
#pragma unroll
        for (int i = 0; i < 4; ++i)
#pragma unroll
            for (int r = 0; r < 4; ++r) {
                const int row = mw + 16 * i + quad * 4 + r;
                const int col = nw + 16 * jt + l15;
                const float v = acc[i][jt][r];
                Gb[(size_t)(m0 + row) * E_ + n0 + col] = v;
                if (!diag) Gb[(size_t)(n0 + col) * E_ + m0 + row] = v;
            }
}

// ---------------------------------------------------------------------------
// Per (b,h): Z = Wq_h G (diag in fp32); L = 0.125(Z Wk^T + biases);
// P = softmax; Wo = P Wv (bf16 to ws); bo = P bv.
// smem phases: A: GB@0(32K) WQ@32K(16K) | B: ZH@0 ZL@16K KH@32K KL@48K | C: PB@0 WVT@16K
// ---------------------------------------------------------------------------
__global__ __launch_bounds__(256) void attn_wo_kernel(
    const float* __restrict__ G,
    const float* __restrict__ WqF, const float* __restrict__ bqF,
    const float* __restrict__ WkF, const float* __restrict__ bkF,
    const float* __restrict__ WvF, const float* __restrict__ bvF,
    const float* __restrict__ uq, const float* __restrict__ uk,
    const float* __restrict__ gdiag,
    unsigned short* __restrict__ Wo, float* __restrict__ bo)
{
    const int bh = blockIdx.x, b = bh >> 4, h = bh & 15;
    const int t = threadIdx.x, lane = t & 63, w = t >> 6;
    const int l15 = lane & 15, quad = lane >> 4;

    __shared__ __align__(16) unsigned char smem[65536];
    unsigned short* GB  = (unsigned short*)(smem);
    unsigned short* WQ  = (unsigned short*)(smem + 32768);
    unsigned short* ZH  = (unsigned short*)(smem);
    unsigned short* ZL  = (unsigned short*)(smem + 16384);
    unsigned short* KH  = (unsigned short*)(smem + 32768);
    unsigned short* KL  = (unsigned short*)(smem + 49152);
    unsigned short* PB  = (unsigned short*)(smem);           // 64 x 72
    unsigned short* WVT = (unsigned short*)(smem + 16384);   // 64 x 64 swz

    const float* Gb  = G   + (size_t)b * E_ * E_;
    const float* Wqh = WqF + (size_t)(h * 64) * E_;
    const float* Wkh = WkF + (size_t)(h * 64) * E_;
    const float* Wvh = WvF + (size_t)(h * 64) * E_;
    const float* gdb = gdiag + b * E_;

    const floatx4 fz = {0.f, 0.f, 0.f, 0.f};
    floatx4 lacc[4] = {fz, fz, fz, fz};

    for (int ic = 0; ic < 8; ++ic) {
        floatx4 zacc[4][2];
#pragma unroll
        for (int mt = 0; mt < 4; ++mt) { zacc[mt][0] = fz; zacc[mt][1] = fz; }

        for (int jc = 0; jc < 8; ++jc) {
            __syncthreads();
#pragma unroll
            for (int it = 0; it < 8; ++it) {       // WQ: 64x128 from Wq_h cols jc*128
                const int l = t + 256 * it;        // 0..2047
                const int c4 = l & 31, row = l >> 5;
                float4 v = *(const float4*)(Wqh + (size_t)row * E_ + jc * 128 + c4 * 4);
                ushort4 o = { f2bf(v.x), f2bf(v.y), f2bf(v.z), f2bf(v.w) };
                *(ushort4*)&WQ[row * 128 + (((c4 >> 1) ^ (row & 15)) << 3) + (c4 & 1) * 4] = o;
            }
#pragma unroll
            for (int it = 0; it < 16; ++it) {      // GB: 128x128 from G rows ic*128, cols jc*128
                const int l = t + 256 * it;        // 0..4095
                const int c4 = l & 31, row = l >> 5;
                float4 v = *(const float4*)(Gb + (size_t)(ic * 128 + row) * E_ + jc * 128 + c4 * 4);
                ushort4 o = { f2bf(v.x), f2bf(v.y), f2bf(v.z), f2bf(v.w) };
                if (ic == jc) {                    // zero the exact diagonal element
                    const int dj = row - c4 * 4;
                    if (dj >= 0 && dj < 4) ((unsigned short*)&o)[dj] = 0;
                }
                *(ushort4*)&GB[row * 128 + (((c4 >> 1) ^ (row & 15)) << 3) + (c4 & 1) * 4] = o;
            }
            __syncthreads();
#pragma unroll
            for (int ks = 0; ks < 4; ++ks) {
                short8 af[4], bfr[2];
#pragma unroll
                for (int mt = 0; mt < 4; ++mt)
                    af[mt] = lds_load8(&WQ[rk_idx(16 * mt + l15, ks * 32 + quad * 8)]);
#pragma unroll
                for (int nt = 0; nt < 2; ++nt)
                    bfr[nt] = lds_load8(&GB[rk_idx(32 * w + 16 * nt + l15, ks * 32 + quad * 8)]);
#pragma unroll
                for (int mt = 0; mt < 4; ++mt)
#pragma unroll
                    for (int nt = 0; nt < 2; ++nt)
                        zacc[mt][nt] = MFMA(af[mt], bfr[nt], zacc[mt][nt]);
            }
        }
        __syncthreads();   // GB/WQ dead; phase B begins
        // dump Z hi/lo with exact fp32 diagonal contribution
#pragma unroll
        for (int mt = 0; mt < 4; ++mt)
#pragma unroll
            for (int nt = 0; nt < 2; ++nt)
#pragma unroll
                for (int r = 0; r < 4; ++r) {
                    const int d = 16 * mt + quad * 4 + r;
                    const int icol = 32 * w + 16 * nt + l15;
                    const int gi = ic * 128 + icol;
                    float v = zacc[mt][nt][r] + Wqh[(size_t)d * E_ + gi] * gdb[gi];
                    const unsigned short hi = f2bf(v);
                    const unsigned short lo = f2bf(v - bf2f(hi));
                    ZH[rk_idx(d, icol)] = hi;
                    ZL[rk_idx(d, icol)] = lo;
                }
        // stage Wk chunk hi/lo
#pragma unroll
        for (int it = 0; it < 8; ++it) {
            const int l = t + 256 * it;
            const int c4 = l & 31, row = l >> 5;
            float4 v = *(const float4*)(Wkh + (size_t)row * E_ + ic * 128 + c4 * 4);
            const float vv[4] = {v.x, v.y, v.z, v.w};
            ushort4 ohi, olo;
#pragma unroll
            for (int j = 0; j < 4; ++j) {
                const unsigned short hi = f2bf(vv[j]);
                ((unsigned short*)&ohi)[j] = hi;
                ((unsigned short*)&olo)[j] = f2bf(vv[j] - bf2f(hi));
            }
            const int off = row * 128 + (((c4 >> 1) ^ (row & 15)) << 3) + (c4 & 1) * 4;
            *(ushort4*)&KH[off] = ohi;
            *(ushort4*)&KL[off] = olo;
        }
        __syncthreads();
        // L += (Zhi+Zlo)(Wkhi+Wklo)^T  (drop lo*lo)
#pragma unroll
        for (int ks = 0; ks < 4; ++ks) {
            const short8 ah = lds_load8(&ZH[rk_idx(16 * w + l15, ks * 32 + quad * 8)]);
            const short8 al = lds_load8(&ZL[rk_idx(16 * w + l15, ks * 32 + quad * 8)]);
#pragma unroll
            for (int jt = 0; jt < 4; ++jt) {
                const short8 bh_ = lds_load8(&KH[rk_idx(16 * jt + l15, ks * 32 + quad * 8)]);
                const short8 bl_ = lds_load8(&KL[rk_idx(16 * jt + l15, ks * 32 + quad * 8)]);
                lacc[jt] = MFMA(ah, bh_, lacc[jt]);
                lacc[jt] = MFMA(ah, bl_, lacc[jt]);
                lacc[jt] = MFMA(al, bh_, lacc[jt]);
            }
        }
    }

    // bias + scale + softmax. Row d = 16w+quad*4+r; col e = 16jt+l15.
    float ukv[4], bkv[4];
#pragma unroll
    for (int jt = 0; jt < 4; ++jt) {
        const int he = h * 64 + 16 * jt + l15;
        ukv[jt] = uk[b * E_ + he];
        bkv[jt] = bkF[he];
    }
    float L[4][4];
#pragma unroll
    for (int r = 0; r < 4; ++r) {
        const int hd = h * 64 + 16 * w + quad * 4 + r;
        const float uqr = uq[b * E_ + hd];
        const float bqr = bqF[hd];
#pragma unroll
        for (int jt = 0; jt < 4; ++jt)
            L[jt][r] = 0.125f * (lacc[jt][r] + bqr * ukv[jt] + bkv[jt] * uqr
                                 + 4096.f * bqr * bkv[jt]);
    }
#pragma unroll
    for (int r = 0; r < 4; ++r) {
        float m = fmaxf(fmaxf(L[0][r], L[1][r]), fmaxf(L[2][r], L[3][r]));
#pragma unroll
        for (int mask = 1; mask < 16; mask <<= 1) m = fmaxf(m, __shfl_xor(m, mask, 64));
        float s = 0.f;
#pragma unroll
        for (int jt = 0; jt < 4; ++jt) { L[jt][r] = __expf(L[jt][r] - m); s += L[jt][r]; }
#pragma unroll
        for (int mask = 1; mask < 16; mask <<= 1) s += __shfl_xor(s, mask, 64);
        const float inv = 1.f / s;
#pragma unroll
        for (int jt = 0; jt < 4; ++jt) L[jt][r] *= inv;
    }

    __syncthreads();   // all waves done with ZH region before PB overwrite
#pragma unroll
    for (int jt = 0; jt < 4; ++jt)
#pragma unroll
        for (int r = 0; r < 4; ++r)
            PB[(16 * w + quad * 4 + r) * 72 + 16 * jt + l15] = f2bf(L[jt][r]);
    __syncthreads();

    if (t < 64) {
        float s = 0.f;
        for (int e = 0; e < 64; ++e) s += bf2f(PB[t * 72 + e]) * bvF[h * 64 + e];
        bo[b * E_ + h * 64 + t] = s;
    }

    // Wo[hd, nc*64..] = sum_e P[d,e] Wv[he, nc*64..]
    unsigned short* Wob = Wo + (size_t)b * E_ * E_;
    for (int nc = 0; nc < 16; ++nc) {
        __syncthreads();
#pragma unroll
        for (int it = 0; it < 4; ++it) {     // WVT[n][e] transposed from Wv rows
            const int l = t + 256 * it;      // 0..1023
            const int n4 = l & 15, e = l >> 4;   // e 0..63
            float4 v = *(const float4*)(Wvh + (size_t)e * E_ + nc * 64 + n4 * 4);
            const float vv[4] = {v.x, v.y, v.z, v.w};
#pragma unroll
            for (int j = 0; j < 4; ++j) {
                const int n = n4 * 4 + j;
                WVT[n * 64 + swz(e >> 3, n) * 8 + (e & 7)] = f2bf(vv[j]);
            }
        }
        __syncthreads();
        floatx4 oacc[4] = {fz, fz, fz, fz};
#pragma unroll
        for (int ks = 0; ks < 2; ++ks) {
            const short8 a = lds_load8(&PB[(16 * w + l15) * 72 + ks * 32 + quad * 8]);
            const int q = ks * 4 + quad;
#pragma unroll
            for (int jt = 0; jt < 4; ++jt) {
                const int row = 16 * jt + l15;
                const short8 bb = lds_load8(&WVT[row * 64 + swz(q, row) * 8]);
                oacc[jt] = MFMA(a, bb, oacc[jt]);
            }
        }
#pragma unroll
        for (int jt = 0; jt < 4; ++jt)
#pragma unroll
            for (int r = 0; r < 4; ++r)
                Wob[(size_t)(h * 64 + 16 * w + quad * 4 + r) * E_ + nc * 64 + 16 * jt + l15]
                    = f2bf(oacc[jt][r]);
    }
}

// ---------------------------------------------------------------------------
// Out_b = X_b Wo_b^T + bo  (fp32 out). 128x128 tile, BK=32.
// ---------------------------------------------------------------------------
#define SWIZ(row, q) ((q) ^ (((row) >> 1) & 3))

__global__ __launch_bounds__(256) void out_gemm_kernel(
    const float* __restrict__ X, const unsigned short* __restrict__ Wo,
    const float* __restrict__ bo, float* __restrict__ Out)
{
    const int b = blockIdx.z;
    const int n0 = blockIdx.x * 128;
    const int m0 = blockIdx.y * 128;
    const int t = threadIdx.x, lane = t & 63, w = t >> 6;
    const int l15 = lane & 15, quad = lane >> 4;
    const int mw = 64 * (w >> 1), nw = 64 * (w & 1);

    __shared__ __align__(16) unsigned short As[128 * 32];
    __shared__ __align__(16) unsigned short Bs[128 * 32];

    const float* Xb = X + (size_t)b * S_ * E_;
    const unsigned short* Wb = Wo + (size_t)b * E_ * E_;
    const float* bob = bo + b * E_;
    float* Ob = Out + (size_t)b * S_ * E_;

    const floatx4 fz = {0.f, 0.f, 0.f, 0.f};
    floatx4 acc[4][4];
#pragma unroll
    for (int i = 0; i < 4; ++i)
#pragma unroll
        for (int j = 0; j < 4; ++j) acc[i][j] = fz;

    for (int k0 = 0; k0 < E_; k0 += 32) {
        __syncthreads();
#pragma unroll
        for (int it = 0; it < 4; ++it) {     // A: 128x32 fp32 -> bf16
            const int l = t + 256 * it;      // 0..1023
            const int c4 = l & 7, row = l >> 3;
            float4 v = *(const float4*)(Xb + (size_t)(m0 + row) * E_ + k0 + c4 * 4);
            ushort4 o = { f2bf(v.x), f2bf(v.y), f2bf(v.z), f2bf(v.w) };
            *(ushort4*)&As[row * 32 + SWIZ(row, c4 >> 1) * 8 + (c4 & 1) * 4] = o;
        }
#pragma unroll
        for (int it = 0; it < 2; ++it) {     // B: 128x32 bf16 (16B chunks)
            const int l = t + 256 * it;      // 0..511
            const int ch = l & 3, row = l >> 2;
            uint4 v = *(const uint4*)(Wb + (size_t)(n0 + row) * E_ + k0 + ch * 8);
            *(uint4*)&Bs[row * 32 + SWIZ(row, ch) * 8] = v;
        }
        __syncthreads();
        short8 af[4], bfr[4];
#pragma unroll
        for (int i = 0; i < 4; ++i) {
            const int row = mw + 16 * i + l15;
            af[i] = lds_load8(&As[row * 32 + SWIZ(row, quad) * 8]);
        }
#pragma unroll
        for (int j = 0; j < 4; ++j) {
            const int row = nw + 16 * j + l15;
            bfr[j] = lds_load8(&Bs[row * 32 + SWIZ(row, quad) * 8]);
        }
#pragma unroll
        for (int i = 0; i < 4; ++i)
#pragma unroll
            for (int j = 0; j < 4; ++j)
                acc[i][j] = MFMA(af[i], bfr[j], acc[i][j]);
    }

#pragma unroll
    for (int jt = 0; jt < 4; ++jt) {
        const int n = n0 + nw + 16 * jt + l15;
        const float bv_ = bob[n];
        float* colp = Ob + n;
#pragma unroll
        for (int i = 0; i < 4; ++i)
#pragma unroll
            for (int r = 0; r < 4; ++r) {
                const int m = m0 + mw + 16 * i + quad * 4 + r;
                colp[(size_t)m * E_] = acc[i][jt][r] + bv_;
            }
    }
}

// ---------------------------------------------------------------------------
extern "C" void kernel_launch(void* const* d_in, const int* in_sizes, int n_in,
                              void* d_out, int out_size, void* d_ws, size_t ws_size,
                              hipStream_t stream) {
    (void)in_sizes; (void)n_in; (void)out_size; (void)ws_size;
    const float* x  = (const float*)d_in[0];
    const float* Wq = (const float*)d_in[1];
    const float* bq = (const float*)d_in[2];
    const float* Wk = (const float*)d_in[3];
    const float* bk = (const float*)d_in[4];
    const float* Wv = (const float*)d_in[5];
    const float* bv = (const float*)d_in[6];

    // ws: Wo bf16 (16 MiB) | cpart,d2part (1 MiB) | c,gdiag,uq,uk,bo (160 KiB)
    unsigned short* Wo = (unsigned short*)d_ws;
    float* cpart  = (float*)(Wo + (size_t)B_ * E_ * E_);
    float* d2part = cpart  + 16 * B_ * E_;
    float* c      = d2part + 16 * B_ * E_;
    float* gdiag  = c      + B_ * E_;
    float* uq     = gdiag  + B_ * E_;
    float* uk     = uq     + B_ * E_;
    float* bo     = uk     + B_ * E_;

    // G fp32 lives in d_out's first 32 MiB; out_gemm overwrites it last.
    float* G = (float*)d_out;

    sums_kernel<<<dim3(4, 8, 16), 256, 0, stream>>>(x, cpart, d2part);
    reduce_kernel<<<dim3(32), 256, 0, stream>>>(cpart, d2part, c, gdiag);
    uqk_kernel<<<dim3(4, 8), 256, 0, stream>>>(Wq, Wk, c, uq, uk);
    gram_kernel<<<dim3(36, 8), 256, 0, stream>>>(x, G);
    attn_wo_kernel<<<dim3(128), 256, 0, stream>>>(G, Wq, bq, Wk, bk, Wv, bv,
                                                  uq, uk, gdiag, Wo, bo);
    out_gemm_kernel<<<dim3(8, 32, 8), 256, 0, stream>>>(x, Wo, bo, (float*)d_out);
}